// Round 5
// baseline (1084.607 us; speedup 1.0000x reference)
//
#include <hip/hip_runtime.h>
#include <hip/hip_bf16.h>
#include <math.h>

// R5: MFMA + K-split. 64 blocks x 16 rows, 8 waves (ns=N-slice, kh=K-half).
// Each wave computes K-half partials of every matvec; f32 partials staged in
// LDS for the opposite half's rows; each wave applies nonlinearity + bf16
// staging for its 2 owned rows only. Fast transcendentals (__expf/__logf/rcp)
// + v_cvt_pk_bf16_f32. Weights pre-packed per (wave,frag) in d_ws.
// eps ~= 0 approximation unchanged (passed R1-R4).

#define TT   128
#define NZN  5
#define ADIM 20
#define ROWS 16
#define FRW  37

typedef __attribute__((ext_vector_type(8))) short short8;
typedef __attribute__((ext_vector_type(4))) float f32x4;

__device__ __forceinline__ float reluf(float x) { return fmaxf(x, 0.f); }
__device__ __forceinline__ float frcp(float x)  { return __builtin_amdgcn_rcpf(x); }
__device__ __forceinline__ float fexp(float x)  { return __expf(x); }
__device__ __forceinline__ float flog(float x)  { return __logf(x); }
__device__ __forceinline__ float fsigm(float x) { return frcp(1.f + fexp(-x)); }
__device__ __forceinline__ float ftanh(float x) {
    float cx = fminf(fmaxf(x, -15.f), 15.f);
    float e2 = fexp(2.f * cx);
    return 1.f - 2.f * frcp(e2 + 1.f);
}
__device__ __forceinline__ float fsoftplus(float x) {
    return fmaxf(x, 0.f) + flog(1.f + fexp(-fabsf(x)));
}
__device__ __forceinline__ unsigned int pk2bf(float lo, float hi) {
    unsigned int r;
    asm volatile("v_cvt_pk_bf16_f32 %0, %1, %2" : "=v"(r) : "v"(lo), "v"(hi));
    return r;
}
__device__ __forceinline__ short8 pack8(float v0, float v1, float v2, float v3,
                                        float v4, float v5, float v6, float v7) {
    union { short8 s; unsigned int u[4]; } r;
    r.u[0] = pk2bf(v0, v1); r.u[1] = pk2bf(v2, v3);
    r.u[2] = pk2bf(v4, v5); r.u[3] = pk2bf(v6, v7);
    return r.s;
}
// stage 2 bf16 values at rows (rw0, rw0+1), logical col `col`, swizzled
__device__ __forceinline__ void stage2(short* buf, int shift, int rw0, int col,
                                       float v0, float v1) {
    unsigned int u = pk2bf(v0, v1);
    buf[(rw0 << shift) + (col ^ ((rw0 & 7) << 3))]             = (short)(u & 0xffff);
    buf[((rw0 + 1) << shift) + (col ^ (((rw0 + 1) & 7) << 3))] = (short)(u >> 16);
}
__device__ __forceinline__ int psidx(int rw, int fc) {
    return rw * 64 + (fc ^ (((rw >> 2) & 3) << 3));
}
__device__ __forceinline__ void split4(const f32x4& x, int kh,
                                       float& oA, float& oB, float& wA, float& wB) {
    if (kh == 0) { oA = x[0]; oB = x[1]; wA = x[2]; wB = x[3]; }
    else         { oA = x[2]; oB = x[3]; wA = x[0]; wB = x[1]; }
}
__device__ __forceinline__ short8 lda64(const short* b, int c, int col0) {
    return *(const short8*)(b + c * 64 + (col0 ^ ((c & 7) << 3)));
}
__device__ __forceinline__ short8 lda128(const short* b, int c, int col0) {
    return *(const short8*)(b + c * 128 + (col0 ^ ((c & 7) << 3)));
}
__device__ __forceinline__ unsigned short f2bf(float x) {
    union { float f; unsigned int u; } v; v.f = x;
    unsigned int r = v.u + 0x7fffu + ((v.u >> 16) & 1u);
    return (unsigned short)(r >> 16);
}
__device__ __forceinline__ float wave_sum64(float v) {
#pragma unroll
    for (int off = 32; off > 0; off >>= 1) v += __shfl_xor(v, off, 64);
    return v;
}
#define MFMA(a, b, acc) __builtin_amdgcn_mfma_f32_16x16x32_bf16((a), (b), (acc), 0, 0, 0)

__global__ void vrnn_zero(float* out) { out[22528] = 0.f; }

// pack: frag (w=0..7, f=0..36, lane l): short8 of B[k=k0+8*(l>>4)+j][ncol]
__global__ __launch_bounds__(256) void vrnn_pack(
    const float* __restrict__ W_x,  const float* __restrict__ Wp1,
    const float* __restrict__ Wq1,  const float* __restrict__ Wp2,
    const float* __restrict__ Wq2,  const float* __restrict__ W_z,
    const float* __restrict__ W_ih, const float* __restrict__ W_hh,
    short* __restrict__ ws)
{
    const int tid = blockIdx.x * blockDim.x + threadIdx.x;  // 74*256 = 8*37*64
    const int l = tid & 63, f = (tid >> 6) % FRW, w = (tid >> 6) / FRW;
    if (w >= 8) return;
    const int ns = w & 3, kh = w >> 2;
    const int gp_ = l >> 4, cc = l & 15;
    const int fcp = 16 * ns + cc;
    const float* src; int ld = 64, ncol = fcp, k0;
    if (f < 2)       { src = W_x;  k0 = 64 * kh + 32 * f; }
    else if (f < 12) { int r = f - 2;  int n = r >> 1, kt = r & 1;
                       src = Wp1 + n * 8192; k0 = 64 * kh + 32 * kt; }
    else if (f < 17) { src = Wq1 + (f - 12) * 4096; k0 = 32 * kh; }
    else if (f < 22) { src = Wp2 + (f - 17) * 4096; k0 = 32 * kh; }
    else if (f < 27) { src = Wq2 + (f - 22) * 4096; k0 = 32 * kh; }
    else if (f == 27){ src = W_z;  k0 = 32 * kh; }
    else if (f < 34) { int r = f - 28; int gate = r >> 1, kt = r & 1;
                       src = W_ih; ld = 192; ncol = gate * 64 + fcp; k0 = 64 * kh + 32 * kt; }
    else             { int gate = f - 34;
                       src = W_hh; ld = 192; ncol = gate * 64 + fcp; k0 = 32 * kh; }
    short8 frag;
#pragma unroll
    for (int j = 0; j < 8; ++j)
        frag[j] = (short)f2bf(src[(k0 + 8 * gp_ + j) * ld + ncol]);
    *(short8*)(ws + ((w * FRW + f) * 64 + l) * 8) = frag;
}

__global__ __launch_bounds__(512, 2) void vrnn_main(
    const int* __restrict__ acts, const float* __restrict__ durs,
    const float* __restrict__ W_act, const float* __restrict__ b_act,
    const float* __restrict__ W_dur, const float* __restrict__ b_dur,
    const float* __restrict__ b_x, const float* __restrict__ b_z,
    const float* __restrict__ bp1, const float* __restrict__ bq1,
    const float* __restrict__ bp2, const float* __restrict__ bq2,
    const float* __restrict__ b_ih, const float* __restrict__ b_hh,
    const float* __restrict__ g_post, const float* __restrict__ g_prior,
    const float* __restrict__ Wq1, const float* __restrict__ Wq2,
    const float* __restrict__ W_z, const float* __restrict__ W_dec,
    const float* __restrict__ b_dec, const float* __restrict__ W_a,
    const float* __restrict__ b_a, const float* __restrict__ W_durd,
    const float* __restrict__ b_durd,
    const short* __restrict__ ws, float* __restrict__ d_out)
{
    const int w  = threadIdx.x >> 6;
    const int l  = threadIdx.x & 63;
    const int ns = w & 3, kh = w >> 2;
    const int g  = l >> 4, c = l & 15;
    const int fc = 16 * ns + c;
    const int row0 = blockIdx.x * ROWS;
    const int ro = 2 * kh;            // owned r: kh0 -> rows r{0,1}, kh1 -> r{2,3}
    const int wo = 2 - 2 * kh;        // rows written for the other half
    const int rA = 4 * g + ro, rB = rA + 1;
    const int rWA = 4 * g + wo, rWB = rWA + 1;

    __shared__ __align__(16) short s_xz[ROWS * 128];       // [phi_x | phi_z]
    __shared__ __align__(16) short s_h[ROWS * 64];
    __shared__ __align__(16) short s_h1p[NZN][ROWS * 64];
    __shared__ __align__(16) short s_h1q[NZN][ROWS * 64];
    __shared__ __align__(16) short s_z[ROWS * 64];
    __shared__ __align__(16) float s_ps[10][ROWS * 64];    // f32 partials
    __shared__ float s_hf[ROWS * 64];
    __shared__ float s_fin[8][320];
    __shared__ float s_klsum[ROWS];

    const short8* Bw = ((const short8*)ws) + (w * FRW) * 64 + l;
    const f32x4 Z4 = {0.f, 0.f, 0.f, 0.f};

    const float bxr = b_x[fc], bzr = b_z[fc];
    float bp1r[NZN], bq1r[NZN], gp[NZN], gq[NZN];
    float cp2 = 0.f, cq2 = 0.f;
#pragma unroll
    for (int n = 0; n < NZN; ++n) {
        gp[n] = g_post[n]; gq[n] = g_prior[n];
        bp1r[n] = bp1[n * 64 + fc]; bq1r[n] = bq1[n * 64 + fc];
        cp2 = fmaf(gp[n], bp2[n * 64 + fc], cp2);
        cq2 = fmaf(gq[n], bq2[n * 64 + fc], cq2);
    }
    const float bih0 = b_ih[fc], bih1 = b_ih[64 + fc], bih2 = b_ih[128 + fc];
    const float bhh0 = b_hh[fc], bhh1 = b_hh[64 + fc], bhh2 = b_hh[128 + fc];

    float hA = 0.f, hB = 0.f, klA = 0.f, klB = 0.f;

    for (int i = threadIdx.x; i < ROWS * 64; i += 512) s_h[i] = 0;
    if (threadIdx.x < ROWS) s_klsum[threadIdx.x] = 0.f;

    for (int t = 0; t < TT; ++t) {
        __syncthreads();                                        // B0
        // ---------- P1: input embed + W_x ----------
        short8 e0, e1;
        if (kh == 0) {
            const int arow = acts[(row0 + c) * TT + t];
            const float4* wa4 = (const float4*)(W_act + arow * 64 + 8 * g);
            const float4* ba4 = (const float4*)(b_act + 8 * g);
            float4 w0 = wa4[0], w1 = wa4[1], w2 = wa4[8], w3 = wa4[9];
            float4 b0 = ba4[0], b1 = ba4[1], b2 = ba4[8], b3 = ba4[9];
            e0 = pack8(reluf(w0.x + b0.x), reluf(w0.y + b0.y), reluf(w0.z + b0.z), reluf(w0.w + b0.w),
                       reluf(w1.x + b1.x), reluf(w1.y + b1.y), reluf(w1.z + b1.z), reluf(w1.w + b1.w));
            e1 = pack8(reluf(w2.x + b2.x), reluf(w2.y + b2.y), reluf(w2.z + b2.z), reluf(w2.w + b2.w),
                       reluf(w3.x + b3.x), reluf(w3.y + b3.y), reluf(w3.z + b3.z), reluf(w3.w + b3.w));
        } else {
            const float dur = durs[(row0 + c) * TT + t];
            const float4* wd4 = (const float4*)(W_dur + 8 * g);
            const float4* bd4 = (const float4*)(b_dur + 8 * g);
            float4 w0 = wd4[0], w1 = wd4[1], w2 = wd4[8], w3 = wd4[9];
            float4 b0 = bd4[0], b1 = bd4[1], b2 = bd4[8], b3 = bd4[9];
            e0 = pack8(reluf(fmaf(dur, w0.x, b0.x)), reluf(fmaf(dur, w0.y, b0.y)),
                       reluf(fmaf(dur, w0.z, b0.z)), reluf(fmaf(dur, w0.w, b0.w)),
                       reluf(fmaf(dur, w1.x, b1.x)), reluf(fmaf(dur, w1.y, b1.y)),
                       reluf(fmaf(dur, w1.z, b1.z)), reluf(fmaf(dur, w1.w, b1.w)));
            e1 = pack8(reluf(fmaf(dur, w2.x, b2.x)), reluf(fmaf(dur, w2.y, b2.y)),
                       reluf(fmaf(dur, w2.z, b2.z)), reluf(fmaf(dur, w2.w, b2.w)),
                       reluf(fmaf(dur, w3.x, b3.x)), reluf(fmaf(dur, w3.y, b3.y)),
                       reluf(fmaf(dur, w3.z, b3.z)), reluf(fmaf(dur, w3.w, b3.w)));
        }
        {
            f32x4 x = Z4;
            x = MFMA(e0, Bw[0], x);
            x = MFMA(e1, Bw[64], x);
            float xoA, xoB, xwA, xwB;
            split4(x, kh, xoA, xoB, xwA, xwB);
            s_ps[0][psidx(rWA, fc)] = xwA;
            s_ps[0][psidx(rWB, fc)] = xwB;
            __syncthreads();                                    // B1a
            float vA = reluf(xoA + s_ps[0][psidx(rA, fc)] + bxr);
            float vB = reluf(xoB + s_ps[0][psidx(rB, fc)] + bxr);
            stage2(s_xz, 7, rA, fc, vA, vB);
        }
        __syncthreads();                                        // B1b

        // ---------- P2: mix layer-1 ----------
        short8 fA0, fA1, fQ;
        if (kh == 0) {
            fA0 = lda128(s_xz, c, 8 * g);
            fA1 = lda128(s_xz, c, 32 + 8 * g);
            fQ  = lda64(s_h, c, 8 * g);
        } else {
            fA0 = lda64(s_h, c, 8 * g);
            fA1 = lda64(s_h, c, 32 + 8 * g);
            fQ  = fA1;
        }
        {
            float opA[NZN], opB[NZN], oqA[NZN], oqB[NZN];
#pragma unroll
            for (int n = 0; n < NZN; ++n) {
                f32x4 p = Z4;
                p = MFMA(fA0, Bw[(2 + 2 * n) * 64], p);
                p = MFMA(fA1, Bw[(3 + 2 * n) * 64], p);
                f32x4 q = MFMA(fQ, Bw[(12 + n) * 64], Z4);
                float wA_, wB_;
                split4(p, kh, opA[n], opB[n], wA_, wB_);
                s_ps[n][psidx(rWA, fc)] = wA_;
                s_ps[n][psidx(rWB, fc)] = wB_;
                split4(q, kh, oqA[n], oqB[n], wA_, wB_);
                s_ps[NZN + n][psidx(rWA, fc)] = wA_;
                s_ps[NZN + n][psidx(rWB, fc)] = wB_;
            }
            __syncthreads();                                    // B2a
#pragma unroll
            for (int n = 0; n < NZN; ++n) {
                float pA = reluf(opA[n] + s_ps[n][psidx(rA, fc)] + bp1r[n]);
                float pB = reluf(opB[n] + s_ps[n][psidx(rB, fc)] + bp1r[n]);
                stage2(s_h1p[n], 6, rA, fc, pA, pB);
                float qA = reluf(oqA[n] + s_ps[NZN + n][psidx(rA, fc)] + bq1r[n]);
                float qB = reluf(oqB[n] + s_ps[NZN + n][psidx(rB, fc)] + bq1r[n]);
                stage2(s_h1q[n], 6, rA, fc, qA, qB);
            }
        }
        __syncthreads();                                        // B2b

        // ---------- P3: mix layer-2 + gamma + KL + z ----------
        {
            f32x4 mp = Z4, mq = Z4;
#pragma unroll
            for (int n = 0; n < NZN; ++n) {
                short8 hp = (kh == 0) ? lda64(s_h1p[n], c, 8 * g) : lda64(s_h1p[n], c, 32 + 8 * g);
                short8 hq = (kh == 0) ? lda64(s_h1q[n], c, 8 * g) : lda64(s_h1q[n], c, 32 + 8 * g);
                f32x4 p = MFMA(hp, Bw[(17 + n) * 64], Z4);
                f32x4 q = MFMA(hq, Bw[(22 + n) * 64], Z4);
#pragma unroll
                for (int r = 0; r < 4; ++r) {
                    mp[r] = fmaf(gp[n], p[r], mp[r]);
                    mq[r] = fmaf(gq[n], q[r], mq[r]);
                }
            }
            float mpoA, mpoB, mpwA, mpwB, mqoA, mqoB, mqwA, mqwB;
            split4(mp, kh, mpoA, mpoB, mpwA, mpwB);
            split4(mq, kh, mqoA, mqoB, mqwA, mqwB);
            s_ps[0][psidx(rWA, fc)] = mpwA; s_ps[0][psidx(rWB, fc)] = mpwB;
            s_ps[1][psidx(rWA, fc)] = mqwA; s_ps[1][psidx(rWB, fc)] = mqwB;
            __syncthreads();                                    // B3a
            float mpostA = mpoA + s_ps[0][psidx(rA, fc)] + cp2;
            float mpostB = mpoB + s_ps[0][psidx(rB, fc)] + cp2;
            float mpriA  = mqoA + s_ps[1][psidx(rA, fc)] + cq2;
            float mpriB  = mqoB + s_ps[1][psidx(rB, fc)] + cq2;
            float pmA = reluf(mpostA), psA = fsoftplus(mpostA);
            float qmA = reluf(mpriA),  qsA = fsoftplus(mpriA);
            float pmB = reluf(mpostB), psB = fsoftplus(mpostB);
            float qmB = reluf(mpriB),  qsB = fsoftplus(mpriB);
            float dA_ = pmA - qmA, dB_ = pmB - qmB;
            klA += flog(qsA) - flog(psA) + (psA * psA + dA_ * dA_) * 0.5f * frcp(qsA * qsA) - 0.5f;
            klB += flog(qsB) - flog(psB) + (psB * psB + dB_ * dB_) * 0.5f * frcp(qsB * qsB) - 0.5f;
            stage2(s_z, 6, rA, fc, pmA, pmB);
        }
        __syncthreads();                                        // B3b

        // ---------- P4: phi_z ----------
        {
            short8 az = (kh == 0) ? lda64(s_z, c, 8 * g) : lda64(s_z, c, 32 + 8 * g);
            f32x4 zz = MFMA(az, Bw[27 * 64], Z4);
            float zoA, zoB, zwA, zwB;
            split4(zz, kh, zoA, zoB, zwA, zwB);
            s_ps[0][psidx(rWA, fc)] = zwA;
            s_ps[0][psidx(rWB, fc)] = zwB;
            __syncthreads();                                    // B4a
            float pzA = reluf(zoA + s_ps[0][psidx(rA, fc)] + bzr);
            float pzB = reluf(zoB + s_ps[0][psidx(rB, fc)] + bzr);
            stage2(s_xz, 7, rA, 64 + fc, pzA, pzB);
        }
        __syncthreads();                                        // B4b

        // ---------- P5: GRU ----------
        {
            short8 gA0, gA1, gH;
            if (kh == 0) { gA0 = fA0; gA1 = fA1; gH = fQ; }
            else {
                gA0 = lda128(s_xz, c, 64 + 8 * g);
                gA1 = lda128(s_xz, c, 96 + 8 * g);
                gH  = fA1;
            }
            float ogiA[3], ogiB[3], oghA[3], oghB[3];
#pragma unroll
            for (int gt = 0; gt < 3; ++gt) {
                f32x4 gi = Z4;
                gi = MFMA(gA0, Bw[(28 + 2 * gt) * 64], gi);
                gi = MFMA(gA1, Bw[(29 + 2 * gt) * 64], gi);
                f32x4 gh = MFMA(gH, Bw[(34 + gt) * 64], Z4);
                float wA_, wB_;
                split4(gi, kh, ogiA[gt], ogiB[gt], wA_, wB_);
                s_ps[gt][psidx(rWA, fc)] = wA_;
                s_ps[gt][psidx(rWB, fc)] = wB_;
                split4(gh, kh, oghA[gt], oghB[gt], wA_, wB_);
                s_ps[3 + gt][psidx(rWA, fc)] = wA_;
                s_ps[3 + gt][psidx(rWB, fc)] = wB_;
            }
            __syncthreads();                                    // B5a
            float i0A = ogiA[0] + s_ps[0][psidx(rA, fc)] + bih0;
            float i1A = ogiA[1] + s_ps[1][psidx(rA, fc)] + bih1;
            float i2A = ogiA[2] + s_ps[2][psidx(rA, fc)] + bih2;
            float h0A = oghA[0] + s_ps[3][psidx(rA, fc)] + bhh0;
            float h1A = oghA[1] + s_ps[4][psidx(rA, fc)] + bhh1;
            float h2A = oghA[2] + s_ps[5][psidx(rA, fc)] + bhh2;
            float i0B = ogiB[0] + s_ps[0][psidx(rB, fc)] + bih0;
            float i1B = ogiB[1] + s_ps[1][psidx(rB, fc)] + bih1;
            float i2B = ogiB[2] + s_ps[2][psidx(rB, fc)] + bih2;
            float h0B = oghB[0] + s_ps[3][psidx(rB, fc)] + bhh0;
            float h1B = oghB[1] + s_ps[4][psidx(rB, fc)] + bhh1;
            float h2B = oghB[2] + s_ps[5][psidx(rB, fc)] + bhh2;
            float rrA = fsigm(i0A + h0A), zgA = fsigm(i1A + h1A);
            float nnA = ftanh(i2A + rrA * h2A);
            hA = (1.f - zgA) * nnA + zgA * hA;
            float rrB = fsigm(i0B + h0B), zgB = fsigm(i1B + h1B);
            float nnB = ftanh(i2B + rrB * h2B);
            hB = (1.f - zgB) * nnB + zgB * hB;
            stage2(s_h, 6, rA, fc, hA, hB);
        }
        // next-iter B0 orders s_h for readers
    }

    // ================= epilogue =================
    s_hf[rA * 64 + fc] = hA;
    s_hf[rB * 64 + fc] = hB;
    {
        float kA = klA, kB = klB;
#pragma unroll
        for (int off = 1; off < 16; off <<= 1) {
            kA += __shfl_xor(kA, off, 64);
            kB += __shfl_xor(kB, off, 64);
        }
        if (c == 0) {
            atomicAdd(&s_klsum[rA], kA);
            atomicAdd(&s_klsum[rB], kB);
        }
    }
    __syncthreads();

    // final decode: wave w handles rows 2w, 2w+1 (fp32 original weights)
    {
        float* sf = s_fin[w];
        for (int rr = 0; rr < 2; ++rr) {
            const int lr = 2 * w + rr, grow = row0 + lr;
            float accn[NZN];
#pragma unroll
            for (int n = 0; n < NZN; ++n) accn[n] = bq1[n * 64 + l];
            for (int i = 0; i < 64; ++i) {
                const float hv = s_hf[lr * 64 + i];
#pragma unroll
                for (int n = 0; n < NZN; ++n) accn[n] += hv * Wq1[(n * 64 + i) * 64 + l];
            }
#pragma unroll
            for (int n = 0; n < NZN; ++n) sf[n * 64 + l] = reluf(accn[n]);
            float u[NZN];
#pragma unroll
            for (int n = 0; n < NZN; ++n) u[n] = bq2[n * 64 + l];
            for (int o = 0; o < 64; ++o) {
#pragma unroll
                for (int n = 0; n < NZN; ++n) u[n] += sf[n * 64 + o] * Wq2[(n * 64 + o) * 64 + l];
            }
            float mpri = 0.f;
#pragma unroll
            for (int n = 0; n < NZN; ++n) mpri = fmaf(gq[n], u[n], mpri);
            sf[l] = reluf(mpri);                       // z
            float za = b_z[l];
            for (int i = 0; i < 64; ++i) za += sf[i] * W_z[i * 64 + l];
            sf[64 + l] = reluf(za);                    // phi_z
            float dv = b_dec[l];
            for (int i = 0; i < 64; ++i) {
                dv += sf[64 + i] * W_dec[i * 64 + l];
                dv += s_hf[lr * 64 + i] * W_dec[(64 + i) * 64 + l];
            }
            const float dec = reluf(dv);
            sf[128 + l] = dec;
            float lg = 0.f;
            if (l < ADIM) {
                lg = b_a[l];
                for (int o = 0; o < 64; ++o) lg += sf[128 + o] * W_a[o * ADIM + l];
                d_out[grow * ADIM + l] = lg;           // output 0
                sf[192 + l] = lg;
            }
            float pl = b_act[l];
#pragma unroll
            for (int j = 0; j < ADIM; ++j) pl += sf[192 + j] * W_act[j * 64 + l];
            pl = reluf(pl);
            float contrib = pl * W_durd[l] + dec * W_durd[64 + l];
            contrib = wave_sum64(contrib);
            if (l == 0) {
                const float dd = contrib + b_durd[0];
                d_out[20480 + grow] = dd;              // output 1
                d_out[21504 + grow] = fsoftplus(dd);   // output 2
            }
        }
    }
    if (threadIdx.x == 0) {
        float s = 0.f;
#pragma unroll
        for (int i = 0; i < ROWS; ++i) s += s_klsum[i];
        atomicAdd(d_out + 22528, s * (1.f / 1024.f));  // output 3
    }
}

extern "C" void kernel_launch(void* const* d_in, const int* in_sizes, int n_in,
                              void* d_out, int out_size, void* d_ws, size_t ws_size,
                              hipStream_t stream)
{
    const int*   acts    = (const int*)  d_in[0];
    const float* durs    = (const float*)d_in[1];
    const float* W_act   = (const float*)d_in[2];
    const float* b_act   = (const float*)d_in[3];
    const float* W_dur   = (const float*)d_in[4];
    const float* b_dur   = (const float*)d_in[5];
    const float* W_x     = (const float*)d_in[6];
    const float* b_x     = (const float*)d_in[7];
    const float* W_z     = (const float*)d_in[8];
    const float* b_z     = (const float*)d_in[9];
    const float* Wp1     = (const float*)d_in[10];
    const float* bp1     = (const float*)d_in[11];
    const float* Wp2     = (const float*)d_in[12];
    const float* bp2     = (const float*)d_in[13];
    const float* Wq1     = (const float*)d_in[14];
    const float* bq1     = (const float*)d_in[15];
    const float* Wq2     = (const float*)d_in[16];
    const float* bq2     = (const float*)d_in[17];
    const float* W_dec   = (const float*)d_in[18];
    const float* b_dec   = (const float*)d_in[19];
    const float* W_a     = (const float*)d_in[20];
    const float* b_a     = (const float*)d_in[21];
    const float* W_durd  = (const float*)d_in[22];
    const float* b_durd  = (const float*)d_in[23];
    const float* W_ih    = (const float*)d_in[24];
    const float* W_hh    = (const float*)d_in[25];
    const float* b_ih    = (const float*)d_in[26];
    const float* b_hh    = (const float*)d_in[27];
    const float* g_post  = (const float*)d_in[28];
    const float* g_prior = (const float*)d_in[29];
    float* out = (float*)d_out;
    short* ws  = (short*)d_ws;

    vrnn_zero<<<1, 1, 0, stream>>>(out);
    vrnn_pack<<<74, 256, 0, stream>>>(W_x, Wp1, Wq1, Wp2, Wq2, W_z, W_ih, W_hh, ws);
    vrnn_main<<<64, 512, 0, stream>>>(
        acts, durs, W_act, b_act, W_dur, b_dur, b_x, b_z,
        bp1, bq1, bp2, bq2, b_ih, b_hh, g_post, g_prior,
        Wq1, Wq2, W_z, W_dec, b_dec, W_a, b_a, W_durd, b_durd,
        ws, out);
}

// Round 6
// 751.234 us; speedup vs baseline: 1.4438x; 1.4438x over previous
//
#include <hip/hip_runtime.h>
#include <hip/hip_bf16.h>
#include <math.h>

// R6: MFMA + net-level wave split. 64 blocks x 16 rows, 8 waves:
// X-waves (0-3): embed/phi_x -> post-L1 nets0-3 -> post-L2+KL+z -> phi_z -> GRU+h
// H-waves (4-7): prior-L1 + gh   -> net4 + prior-L2(qm/qs) -> gi_x  -> idle
// Every matvec full-K in one wave (no partial reductions); 5 barriers/step.
// f32 cross-group buffers stride-68 padded (2-way conflicts = free).
// eps ~= 0 approximation unchanged (passed R1-R5).

#define TT   128
#define NZN  5
#define ADIM 20
#define ROWS 16
#define FRW  38
#define PS   68   // f32 buffer row stride (conflict-limiting padding)

typedef __attribute__((ext_vector_type(8))) short short8;
typedef __attribute__((ext_vector_type(4))) float f32x4;

__device__ __forceinline__ float reluf(float x) { return fmaxf(x, 0.f); }
__device__ __forceinline__ float frcp(float x)  { return __builtin_amdgcn_rcpf(x); }
__device__ __forceinline__ float fexp(float x)  { return __expf(x); }
__device__ __forceinline__ float flog(float x)  { return __logf(x); }
__device__ __forceinline__ float fsigm(float x) { return frcp(1.f + fexp(-x)); }
__device__ __forceinline__ float ftanh(float x) {
    float cx = fminf(fmaxf(x, -15.f), 15.f);
    float e2 = fexp(2.f * cx);
    return 1.f - 2.f * frcp(e2 + 1.f);
}
__device__ __forceinline__ float fsoftplus(float x) {
    return fmaxf(x, 0.f) + flog(1.f + fexp(-fabsf(x)));
}
__device__ __forceinline__ unsigned int pk2bf(float lo, float hi) {
    unsigned int r;
    asm volatile("v_cvt_pk_bf16_f32 %0, %1, %2" : "=v"(r) : "v"(lo), "v"(hi));
    return r;
}
__device__ __forceinline__ short8 pack8(float v0, float v1, float v2, float v3,
                                        float v4, float v5, float v6, float v7) {
    union { short8 s; unsigned int u[4]; } r;
    r.u[0] = pk2bf(v0, v1); r.u[1] = pk2bf(v2, v3);
    r.u[2] = pk2bf(v4, v5); r.u[3] = pk2bf(v6, v7);
    return r.s;
}
// stage 2 bf16 values at rows (rw0, rw0+1), logical col `col` (XOR-swizzled)
__device__ __forceinline__ void stage2(short* buf, int shift, int rw0, int col,
                                       float v0, float v1) {
    unsigned int u = pk2bf(v0, v1);
    buf[(rw0 << shift) + (col ^ ((rw0 & 7) << 3))]             = (short)(u & 0xffff);
    buf[((rw0 + 1) << shift) + (col ^ (((rw0 + 1) & 7) << 3))] = (short)(u >> 16);
}
__device__ __forceinline__ short8 lda64(const short* b, int c, int col0) {
    return *(const short8*)(b + c * 64 + (col0 ^ ((c & 7) << 3)));
}
__device__ __forceinline__ short8 lda128(const short* b, int c, int col0) {
    return *(const short8*)(b + c * 128 + (col0 ^ ((c & 7) << 3)));
}
__device__ __forceinline__ unsigned short f2bf(float x) {
    union { float f; unsigned int u; } v; v.f = x;
    unsigned int r = v.u + 0x7fffu + ((v.u >> 16) & 1u);
    return (unsigned short)(r >> 16);
}
__device__ __forceinline__ float wave_sum64(float v) {
#pragma unroll
    for (int off = 32; off > 0; off >>= 1) v += __shfl_xor(v, off, 64);
    return v;
}
#define MFMA(a, b, acc) __builtin_amdgcn_mfma_f32_16x16x32_bf16((a), (b), (acc), 0, 0, 0)

__global__ void vrnn_zero(float* out) { out[22528] = 0.f; }

// pack: frag (w 0..7, f 0..FRW-1, lane l): short8 of B[k = k0 + 8*(l>>4) + j][ncol]
__global__ __launch_bounds__(256) void vrnn_pack(
    const float* __restrict__ W_x,  const float* __restrict__ Wp1,
    const float* __restrict__ Wq1,  const float* __restrict__ Wp2,
    const float* __restrict__ Wq2,  const float* __restrict__ W_z,
    const float* __restrict__ W_ih, const float* __restrict__ W_hh,
    short* __restrict__ ws)
{
    const int tid = blockIdx.x * blockDim.x + threadIdx.x;
    if (tid >= 8 * FRW * 64) return;
    const int l = tid & 63, f = (tid >> 6) % FRW, w = (tid >> 6) / FRW;
    const int cc = l & 15, gg = l >> 4;
    const float* src = nullptr; int ld = 64, ncol = 0, k0 = 0;
    if (w < 4) {  // X stream
        const int fcp = 16 * w + cc; ncol = fcp;
        if (f < 4)       { src = W_x;  k0 = 32 * f; }
        else if (f < 20) { int r = f - 4;  int n = r >> 2, q = r & 3;
                           src = Wp1 + n * 8192; k0 = 32 * q; }
        else if (f < 30) { int r = f - 20; int n = r >> 1, q = r & 1;
                           src = Wp2 + n * 4096; k0 = 32 * q; }
        else if (f < 32) { src = W_z;  k0 = 32 * (f - 30); }
        else             { int r = f - 32; int gt = r >> 1, q = r & 1;
                           src = W_ih; ld = 192; ncol = gt * 64 + fcp; k0 = 64 + 32 * q; }
    } else {      // H stream
        const int fcp = 16 * (w - 4) + cc; ncol = fcp;
        if (f < 10)      { int n = f >> 1, q = f & 1;
                           src = Wq1 + n * 4096; k0 = 32 * q; }
        else if (f < 16) { int r = f - 10; int gt = r >> 1, q = r & 1;
                           src = W_hh; ld = 192; ncol = gt * 64 + fcp; k0 = 32 * q; }
        else if (f < 20) { src = Wp1 + 4 * 8192; k0 = 32 * (f - 16); }
        else if (f < 30) { int r = f - 20; int n = r >> 1, q = r & 1;
                           src = Wq2 + n * 4096; k0 = 32 * q; }
        else if (f < 36) { int r = f - 30; int gt = r >> 1, q = r & 1;
                           src = W_ih; ld = 192; ncol = gt * 64 + fcp; k0 = 32 * q; }
        // f 36,37: pad (zeros)
    }
    short8 frag = {0, 0, 0, 0, 0, 0, 0, 0};
    if (src) {
#pragma unroll
        for (int j = 0; j < 8; ++j)
            frag[j] = (short)f2bf(src[(k0 + 8 * gg + j) * ld + ncol]);
    }
    *(short8*)(ws + ((w * FRW + f) * 64 + l) * 8) = frag;
}

__global__ __launch_bounds__(512, 2) void vrnn_main(
    const int* __restrict__ acts, const float* __restrict__ durs,
    const float* __restrict__ W_act, const float* __restrict__ b_act,
    const float* __restrict__ W_dur, const float* __restrict__ b_dur,
    const float* __restrict__ b_x, const float* __restrict__ b_z,
    const float* __restrict__ bp1, const float* __restrict__ bq1,
    const float* __restrict__ bp2, const float* __restrict__ bq2,
    const float* __restrict__ b_ih, const float* __restrict__ b_hh,
    const float* __restrict__ g_post, const float* __restrict__ g_prior,
    const float* __restrict__ Wq1, const float* __restrict__ Wq2,
    const float* __restrict__ W_z, const float* __restrict__ W_dec,
    const float* __restrict__ b_dec, const float* __restrict__ W_a,
    const float* __restrict__ b_a, const float* __restrict__ W_durd,
    const float* __restrict__ b_durd,
    const short* __restrict__ ws, float* __restrict__ d_out)
{
    const int w = threadIdx.x >> 6, l = threadIdx.x & 63;
    const bool isH = (w >= 4);
    const int ns = isH ? (w - 4) : w;
    const int g = l >> 4, c = l & 15;
    const int fc = 16 * ns + c;
    const int row0 = blockIdx.x * ROWS;

    __shared__ __align__(16) short s_xz[ROWS * 128];
    __shared__ __align__(16) short s_h[ROWS * 64];
    __shared__ __align__(16) short s_h1p[NZN][ROWS * 64];
    __shared__ __align__(16) short s_h1q[NZN][ROWS * 64];
    __shared__ __align__(16) short s_z[ROWS * 64];
    __shared__ float s_gh[3][ROWS * PS];
    __shared__ float s_gix[3][ROWS * PS];
    __shared__ float s_qm[ROWS * PS], s_qs[ROWS * PS], s_lqs[ROWS * PS];
    __shared__ float s_hf[ROWS * 64];
    __shared__ float s_fin[8][320];
    __shared__ float s_klsum[ROWS];

    const short8* Bw = ((const short8*)ws) + (w * FRW) * 64 + l;
#define BF(f) Bw[(f) * 64]
    const f32x4 Z4 = {0.f, 0.f, 0.f, 0.f};

    const float bxr = b_x[fc], bzr = b_z[fc];
    float bp1r[NZN], bq1r[NZN], gp[NZN], gq[NZN];
    float cp2 = 0.f, cq2 = 0.f;
#pragma unroll
    for (int n = 0; n < NZN; ++n) {
        gp[n] = g_post[n]; gq[n] = g_prior[n];
        bp1r[n] = bp1[n * 64 + fc]; bq1r[n] = bq1[n * 64 + fc];
        cp2 = fmaf(gp[n], bp2[n * 64 + fc], cp2);
        cq2 = fmaf(gq[n], bq2[n * 64 + fc], cq2);
    }
    const float bih0 = b_ih[fc], bih1 = b_ih[64 + fc], bih2 = b_ih[128 + fc];
    const float bhh0 = b_hh[fc], bhh1 = b_hh[64 + fc], bhh2 = b_hh[128 + fc];

    float hr[4] = {0.f, 0.f, 0.f, 0.f};
    float kl[4] = {0.f, 0.f, 0.f, 0.f};
    float pmv[4];

    for (int i = threadIdx.x; i < ROWS * 64; i += 512) s_h[i] = 0;
    if (threadIdx.x < ROWS) s_klsum[threadIdx.x] = 0.f;

    short8 ax0, ax1, ah0, ah1;

    for (int t = 0; t < TT; ++t) {
        __syncthreads();                                        // B0
        if (!isH) {
            // ---- P1-X: embed + W_x -> phi_x ----
            const int   arow = acts[(row0 + c) * TT + t];
            const float dur  = durs[(row0 + c) * TT + t];
            const float4* wa4 = (const float4*)(W_act + arow * 64 + 8 * g);
            const float4* ba4 = (const float4*)(b_act + 8 * g);
            float4 w0 = wa4[0], w1 = wa4[1], w2 = wa4[8], w3 = wa4[9];
            float4 b0 = ba4[0], b1 = ba4[1], b2 = ba4[8], b3 = ba4[9];
            short8 e0 = pack8(reluf(w0.x + b0.x), reluf(w0.y + b0.y), reluf(w0.z + b0.z), reluf(w0.w + b0.w),
                              reluf(w1.x + b1.x), reluf(w1.y + b1.y), reluf(w1.z + b1.z), reluf(w1.w + b1.w));
            short8 e1 = pack8(reluf(w2.x + b2.x), reluf(w2.y + b2.y), reluf(w2.z + b2.z), reluf(w2.w + b2.w),
                              reluf(w3.x + b3.x), reluf(w3.y + b3.y), reluf(w3.z + b3.z), reluf(w3.w + b3.w));
            const float4* wd4 = (const float4*)(W_dur + 8 * g);
            const float4* bd4 = (const float4*)(b_dur + 8 * g);
            float4 d0 = wd4[0], d1 = wd4[1], d2 = wd4[8], d3 = wd4[9];
            float4 c0 = bd4[0], c1 = bd4[1], c2 = bd4[8], c3 = bd4[9];
            short8 e2 = pack8(reluf(fmaf(dur, d0.x, c0.x)), reluf(fmaf(dur, d0.y, c0.y)),
                              reluf(fmaf(dur, d0.z, c0.z)), reluf(fmaf(dur, d0.w, c0.w)),
                              reluf(fmaf(dur, d1.x, c1.x)), reluf(fmaf(dur, d1.y, c1.y)),
                              reluf(fmaf(dur, d1.z, c1.z)), reluf(fmaf(dur, d1.w, c1.w)));
            short8 e3 = pack8(reluf(fmaf(dur, d2.x, c2.x)), reluf(fmaf(dur, d2.y, c2.y)),
                              reluf(fmaf(dur, d2.z, c2.z)), reluf(fmaf(dur, d2.w, c2.w)),
                              reluf(fmaf(dur, d3.x, c3.x)), reluf(fmaf(dur, d3.y, c3.y)),
                              reluf(fmaf(dur, d3.z, c3.z)), reluf(fmaf(dur, d3.w, c3.w)));
            f32x4 x = Z4;
            x = MFMA(e0, BF(0), x); x = MFMA(e1, BF(1), x);
            x = MFMA(e2, BF(2), x); x = MFMA(e3, BF(3), x);
            stage2(s_xz, 7, 4 * g,     fc, reluf(x[0] + bxr), reluf(x[1] + bxr));
            stage2(s_xz, 7, 4 * g + 2, fc, reluf(x[2] + bxr), reluf(x[3] + bxr));
        } else {
            // ---- P1-H: prior L1 + gh (depend only on h) ----
            ah0 = lda64(s_h, c, 8 * g);
            ah1 = lda64(s_h, c, 32 + 8 * g);
#pragma unroll
            for (int n = 0; n < NZN; ++n) {
                f32x4 q = MFMA(ah0, BF(2 * n), Z4);
                q = MFMA(ah1, BF(2 * n + 1), q);
                stage2(s_h1q[n], 6, 4 * g,     fc, reluf(q[0] + bq1r[n]), reluf(q[1] + bq1r[n]));
                stage2(s_h1q[n], 6, 4 * g + 2, fc, reluf(q[2] + bq1r[n]), reluf(q[3] + bq1r[n]));
            }
#pragma unroll
            for (int gt = 0; gt < 3; ++gt) {
                f32x4 gh = MFMA(ah0, BF(10 + 2 * gt), Z4);
                gh = MFMA(ah1, BF(11 + 2 * gt), gh);
#pragma unroll
                for (int r = 0; r < 4; ++r)
                    s_gh[gt][(4 * g + r) * PS + fc] = gh[r];
            }
        }
        __syncthreads();                                        // B1
        if (!isH) {
            // ---- P2-X: post L1 nets 0-3 ----
            ax0 = lda128(s_xz, c, 8 * g);
            ax1 = lda128(s_xz, c, 32 + 8 * g);
            ah0 = lda64(s_h, c, 8 * g);
            ah1 = lda64(s_h, c, 32 + 8 * g);
#pragma unroll
            for (int n = 0; n < 4; ++n) {
                f32x4 p = MFMA(ax0, BF(4 + 4 * n), Z4);
                p = MFMA(ax1, BF(5 + 4 * n), p);
                p = MFMA(ah0, BF(6 + 4 * n), p);
                p = MFMA(ah1, BF(7 + 4 * n), p);
                stage2(s_h1p[n], 6, 4 * g,     fc, reluf(p[0] + bp1r[n]), reluf(p[1] + bp1r[n]));
                stage2(s_h1p[n], 6, 4 * g + 2, fc, reluf(p[2] + bp1r[n]), reluf(p[3] + bp1r[n]));
            }
        } else {
            // ---- P2-H: post L1 net 4 + prior L2 -> qm/qs/lqs ----
            ax0 = lda128(s_xz, c, 8 * g);
            ax1 = lda128(s_xz, c, 32 + 8 * g);
            {
                f32x4 p = MFMA(ax0, BF(16), Z4);
                p = MFMA(ax1, BF(17), p);
                p = MFMA(ah0, BF(18), p);
                p = MFMA(ah1, BF(19), p);
                stage2(s_h1p[4], 6, 4 * g,     fc, reluf(p[0] + bp1r[4]), reluf(p[1] + bp1r[4]));
                stage2(s_h1p[4], 6, 4 * g + 2, fc, reluf(p[2] + bp1r[4]), reluf(p[3] + bp1r[4]));
            }
            f32x4 mq = Z4;
#pragma unroll
            for (int n = 0; n < NZN; ++n) {
                short8 hq0 = lda64(s_h1q[n], c, 8 * g);
                short8 hq1 = lda64(s_h1q[n], c, 32 + 8 * g);
                f32x4 q = MFMA(hq0, BF(20 + 2 * n), Z4);
                q = MFMA(hq1, BF(21 + 2 * n), q);
#pragma unroll
                for (int r = 0; r < 4; ++r) mq[r] = fmaf(gq[n], q[r], mq[r]);
            }
#pragma unroll
            for (int r = 0; r < 4; ++r) {
                const int rw = 4 * g + r;
                float mpri = mq[r] + cq2;
                float qm = reluf(mpri), qs = fsoftplus(mpri);
                s_qm[rw * PS + fc] = qm;
                s_qs[rw * PS + fc] = qs;
                s_lqs[rw * PS + fc] = flog(qs);
            }
        }
        __syncthreads();                                        // B2
        if (!isH) {
            // ---- P3-X: post L2 + gamma + KL + z ----
            f32x4 mp = Z4;
#pragma unroll
            for (int n = 0; n < NZN; ++n) {
                short8 hp0 = lda64(s_h1p[n], c, 8 * g);
                short8 hp1 = lda64(s_h1p[n], c, 32 + 8 * g);
                f32x4 p = MFMA(hp0, BF(20 + 2 * n), Z4);
                p = MFMA(hp1, BF(21 + 2 * n), p);
#pragma unroll
                for (int r = 0; r < 4; ++r) mp[r] = fmaf(gp[n], p[r], mp[r]);
            }
#pragma unroll
            for (int r = 0; r < 4; ++r) {
                const int rw = 4 * g + r;
                float mpost = mp[r] + cp2;
                float pm = reluf(mpost), ps = fsoftplus(mpost);
                float qm = s_qm[rw * PS + fc];
                float qs = s_qs[rw * PS + fc];
                float lqs = s_lqs[rw * PS + fc];
                float dd = pm - qm;
                kl[r] += lqs - flog(ps) + (ps * ps + dd * dd) * 0.5f * frcp(qs * qs) - 0.5f;
                pmv[r] = pm;
            }
            stage2(s_z, 6, 4 * g,     fc, pmv[0], pmv[1]);
            stage2(s_z, 6, 4 * g + 2, fc, pmv[2], pmv[3]);
        } else {
            // ---- P3-H: gi_x (phi_x part of GRU input gates) ----
#pragma unroll
            for (int gt = 0; gt < 3; ++gt) {
                f32x4 gx = MFMA(ax0, BF(30 + 2 * gt), Z4);
                gx = MFMA(ax1, BF(31 + 2 * gt), gx);
#pragma unroll
                for (int r = 0; r < 4; ++r)
                    s_gix[gt][(4 * g + r) * PS + fc] = gx[r];
            }
        }
        __syncthreads();                                        // B3
        if (!isH) {
            // ---- P4-X: phi_z ----
            short8 az0 = lda64(s_z, c, 8 * g);
            short8 az1 = lda64(s_z, c, 32 + 8 * g);
            f32x4 zz = MFMA(az0, BF(30), Z4);
            zz = MFMA(az1, BF(31), zz);
            stage2(s_xz, 7, 4 * g,     64 + fc, reluf(zz[0] + bzr), reluf(zz[1] + bzr));
            stage2(s_xz, 7, 4 * g + 2, 64 + fc, reluf(zz[2] + bzr), reluf(zz[3] + bzr));
        }
        __syncthreads();                                        // B4
        if (!isH) {
            // ---- P5-X: gi_z + GRU ----
            short8 gz0 = lda128(s_xz, c, 64 + 8 * g);
            short8 gz1 = lda128(s_xz, c, 96 + 8 * g);
            f32x4 gi0 = MFMA(gz0, BF(32), Z4); gi0 = MFMA(gz1, BF(33), gi0);
            f32x4 gi1 = MFMA(gz0, BF(34), Z4); gi1 = MFMA(gz1, BF(35), gi1);
            f32x4 gi2 = MFMA(gz0, BF(36), Z4); gi2 = MFMA(gz1, BF(37), gi2);
#pragma unroll
            for (int r = 0; r < 4; ++r) {
                const int rw = 4 * g + r;
                float i0 = gi0[r] + s_gix[0][rw * PS + fc] + bih0;
                float i1 = gi1[r] + s_gix[1][rw * PS + fc] + bih1;
                float i2 = gi2[r] + s_gix[2][rw * PS + fc] + bih2;
                float h0 = s_gh[0][rw * PS + fc] + bhh0;
                float h1 = s_gh[1][rw * PS + fc] + bhh1;
                float h2 = s_gh[2][rw * PS + fc] + bhh2;
                float rr = fsigm(i0 + h0);
                float zg = fsigm(i1 + h1);
                float nn = ftanh(i2 + rr * h2);
                hr[r] = (1.f - zg) * nn + zg * hr[r];
            }
            stage2(s_h, 6, 4 * g,     fc, hr[0], hr[1]);
            stage2(s_h, 6, 4 * g + 2, fc, hr[2], hr[3]);
        }
    }

    // ================= epilogue =================
    if (!isH) {
#pragma unroll
        for (int r = 0; r < 4; ++r) s_hf[(4 * g + r) * 64 + fc] = hr[r];
#pragma unroll
        for (int off = 1; off < 16; off <<= 1) {
#pragma unroll
            for (int r = 0; r < 4; ++r) kl[r] += __shfl_xor(kl[r], off, 64);
        }
        if (c == 0) {
#pragma unroll
            for (int r = 0; r < 4; ++r) atomicAdd(&s_klsum[4 * g + r], kl[r]);
        }
    }
    __syncthreads();

    // final decode: wave w handles rows 2w, 2w+1 (fp32 original weights)
    {
        float* sf = s_fin[w];
        for (int rr = 0; rr < 2; ++rr) {
            const int lr = 2 * w + rr, grow = row0 + lr;
            float accn[NZN];
#pragma unroll
            for (int n = 0; n < NZN; ++n) accn[n] = bq1[n * 64 + l];
            for (int i = 0; i < 64; ++i) {
                const float hv = s_hf[lr * 64 + i];
#pragma unroll
                for (int n = 0; n < NZN; ++n) accn[n] += hv * Wq1[(n * 64 + i) * 64 + l];
            }
#pragma unroll
            for (int n = 0; n < NZN; ++n) sf[n * 64 + l] = reluf(accn[n]);
            float u[NZN];
#pragma unroll
            for (int n = 0; n < NZN; ++n) u[n] = bq2[n * 64 + l];
            for (int o = 0; o < 64; ++o) {
#pragma unroll
                for (int n = 0; n < NZN; ++n) u[n] += sf[n * 64 + o] * Wq2[(n * 64 + o) * 64 + l];
            }
            float mpri = 0.f;
#pragma unroll
            for (int n = 0; n < NZN; ++n) mpri = fmaf(gq[n], u[n], mpri);
            sf[l] = reluf(mpri);                       // z
            float za = b_z[l];
            for (int i = 0; i < 64; ++i) za += sf[i] * W_z[i * 64 + l];
            sf[64 + l] = reluf(za);                    // phi_z
            float dv = b_dec[l];
            for (int i = 0; i < 64; ++i) {
                dv += sf[64 + i] * W_dec[i * 64 + l];
                dv += s_hf[lr * 64 + i] * W_dec[(64 + i) * 64 + l];
            }
            const float dec = reluf(dv);
            sf[128 + l] = dec;
            float lg = 0.f;
            if (l < ADIM) {
                lg = b_a[l];
                for (int o = 0; o < 64; ++o) lg += sf[128 + o] * W_a[o * ADIM + l];
                d_out[grow * ADIM + l] = lg;           // output 0
                sf[192 + l] = lg;
            }
            float pl = b_act[l];
#pragma unroll
            for (int j = 0; j < ADIM; ++j) pl += sf[192 + j] * W_act[j * 64 + l];
            pl = reluf(pl);
            float contrib = pl * W_durd[l] + dec * W_durd[64 + l];
            contrib = wave_sum64(contrib);
            if (l == 0) {
                const float dd = contrib + b_durd[0];
                d_out[20480 + grow] = dd;              // output 1
                d_out[21504 + grow] = fsoftplus(dd);   // output 2
            }
        }
    }
    if (threadIdx.x == 0) {
        float s = 0.f;
#pragma unroll
        for (int i = 0; i < ROWS; ++i) s += s_klsum[i];
        atomicAdd(d_out + 22528, s * (1.f / 1024.f));  // output 3
    }
#undef BF
}

extern "C" void kernel_launch(void* const* d_in, const int* in_sizes, int n_in,
                              void* d_out, int out_size, void* d_ws, size_t ws_size,
                              hipStream_t stream)
{
    const int*   acts    = (const int*)  d_in[0];
    const float* durs    = (const float*)d_in[1];
    const float* W_act   = (const float*)d_in[2];
    const float* b_act   = (const float*)d_in[3];
    const float* W_dur   = (const float*)d_in[4];
    const float* b_dur   = (const float*)d_in[5];
    const float* W_x     = (const float*)d_in[6];
    const float* b_x     = (const float*)d_in[7];
    const float* W_z     = (const float*)d_in[8];
    const float* b_z     = (const float*)d_in[9];
    const float* Wp1     = (const float*)d_in[10];
    const float* bp1     = (const float*)d_in[11];
    const float* Wp2     = (const float*)d_in[12];
    const float* bp2     = (const float*)d_in[13];
    const float* Wq1     = (const float*)d_in[14];
    const float* bq1     = (const float*)d_in[15];
    const float* Wq2     = (const float*)d_in[16];
    const float* bq2     = (const float*)d_in[17];
    const float* W_dec   = (const float*)d_in[18];
    const float* b_dec   = (const float*)d_in[19];
    const float* W_a     = (const float*)d_in[20];
    const float* b_a     = (const float*)d_in[21];
    const float* W_durd  = (const float*)d_in[22];
    const float* b_durd  = (const float*)d_in[23];
    const float* W_ih    = (const float*)d_in[24];
    const float* W_hh    = (const float*)d_in[25];
    const float* b_ih    = (const float*)d_in[26];
    const float* b_hh    = (const float*)d_in[27];
    const float* g_post  = (const float*)d_in[28];
    const float* g_prior = (const float*)d_in[29];
    float* out = (float*)d_out;
    short* ws  = (short*)d_ws;

    vrnn_zero<<<1, 1, 0, stream>>>(out);
    vrnn_pack<<<76, 256, 0, stream>>>(W_x, Wp1, Wq1, Wp2, Wq2, W_z, W_ih, W_hh, ws);
    vrnn_main<<<64, 512, 0, stream>>>(
        acts, durs, W_act, b_act, W_dur, b_dur, b_x, b_z,
        bp1, bq1, bp2, bq2, b_ih, b_hh, g_post, g_prior,
        Wq1, Wq2, W_z, W_dec, b_dec, W_a, b_a, W_durd, b_durd,
        ws, out);
}